// Round 17
// baseline (981.296 us; speedup 1.0000x reference)
//
#include <hip/hip_runtime.h>
#include <stdint.h>

typedef unsigned short u16;
typedef unsigned int u32;
typedef __attribute__((ext_vector_type(8))) short bf16x8;
typedef __attribute__((ext_vector_type(4))) float f32x4;

#define BATCH 4096
#define NFEAT 16
#define ROWS 8
#define NBLK (BATCH / ROWS)      // 512 blocks -> 2 blocks/CU, 2 chains/SIMD

__device__ __forceinline__ float sigm(float v) { return 1.0f / (1.0f + __expf(-v)); }
__device__ __forceinline__ float tanh_f(float v) { return 1.0f - 2.0f / (__expf(2.0f * v) + 1.0f); }
__device__ __forceinline__ u32 cvtpk(float lo, float hi) {  // 2x f32 -> packed bf16 (RNE)
  u32 d;
  asm("v_cvt_pk_bf16_f32 %0, %1, %2" : "=v"(d) : "v"(lo), "v"(hi));
  return d;
}

__global__ void fill_const(float* out, int n, float c) {
  for (int i = blockIdx.x * blockDim.x + threadIdx.x; i < n; i += gridDim.x * blockDim.x)
    out[i] = c;
}

// R17: R16's 4-wave unit-split MFMA recurrence at 8 rows/block (512 blocks,
// 2 blocks/CU -> 2 independent step-chains per SIMD for latency hiding).
// MFMA rows 8..15 are fake (zero-fed, never stored). Wave wid owns units
// 16wid..16wid+15: 8 MFMAs + epilogue + h-slice write; wave 0 adds the
// x-output tile. h double-buffered in LDS -> one __syncthreads per step.
__global__ __launch_bounds__(256, 2) void gru_mfma4(
    const float* __restrict__ x_in, const float* __restrict__ w_ih,
    const float* __restrict__ w_hh, const float* __restrict__ b_ih,
    const float* __restrict__ b_hh, const float* __restrict__ w_lin,
    const float* __restrict__ b_lin, float* __restrict__ out, int T) {
  __shared__ f32x4 WcF[64][64];     // [k][u] folded (r,z,nin,nhh) f32   64 KB
  __shared__ float WlF[64][16];     // [k][f] w_lin^T                     4 KB
  __shared__ u16 lds_h[2][16][72];  // h bf16 double buffer             4.6 KB
  __shared__ float lds_x0[16][17];  // x0 tile (rows 8-15 zeroed)       1.1 KB

  const int tid = threadIdx.x;
  const int wid = tid >> 6;        // wave = unit-column group
  const int l = tid & 63;
  const int g = l >> 4;            // k-octet group / C row-group
  const int c16 = l & 15;          // col-in-tile / row-in-A
  const int r0 = blockIdx.x * ROWS;
  const int u = wid * 16 + c16;    // owned unit column

  // ---- slice-0 passthrough + x0 stage (rows 0-7 real, 8-15 zero) ----
  {
    float v = 0.0f;
    if (tid < ROWS * 16) {
      v = x_in[r0 * 16 + tid];
      out[(size_t)r0 * 16 + tid] = v;
    }
    lds_x0[tid >> 4][tid & 15] = v;
  }

  // ---- cooperative weight fold: thread owns k = tid&63, u-range [16*wid,+16) ----
  {
    const int k = tid & 63;
    float wl16[16];
#pragma unroll
    for (int f = 0; f < 16; ++f) wl16[f] = w_lin[f * 64 + k];
    if (wid == 0) {
#pragma unroll
      for (int f = 0; f < 16; ++f) WlF[k][f] = wl16[f];
    }
    for (int uu = wid * 16; uu < wid * 16 + 16; ++uu) {
      float fr = w_hh[uu * 64 + k];
      float fz = w_hh[(64 + uu) * 64 + k];
      float fn = 0.0f;
#pragma unroll
      for (int f = 0; f < 16; ++f) {
        fr = fmaf(w_ih[uu * 16 + f], wl16[f], fr);
        fz = fmaf(w_ih[(64 + uu) * 16 + f], wl16[f], fz);
        fn = fmaf(w_ih[(128 + uu) * 16 + f], wl16[f], fn);
      }
      WcF[k][uu] = (f32x4){fr, fz, fn, w_hh[(128 + uu) * 64 + k]};
    }
  }
  __syncthreads();

  // ---- per-lane folded biases for owned unit (+ x bias) ----
  float b_r = b_ih[u] + b_hh[u];
  float b_z = b_ih[64 + u] + b_hh[64 + u];
  float b_n = b_ih[128 + u];
  const float b_hn = b_hh[128 + u];
  const float b_x = b_lin[c16];
#pragma unroll
  for (int f = 0; f < 16; ++f) {
    const float bl = b_lin[f];
    b_r = fmaf(w_ih[u * 16 + f], bl, b_r);
    b_z = fmaf(w_ih[(64 + u) * 16 + f], bl, b_z);
    b_n = fmaf(w_ih[(128 + u) * 16 + f], bl, b_n);
  }

  // ---- resident B-frags for owned planes (+x for wave0) ----
  union U { u32 w[4]; bf16x8 v; };
  bf16x8 Br[2], Bz[2], Bn[2], Bh[2], Bx[2];
#pragma unroll
  for (int kh = 0; kh < 2; ++kh) {
    U ur, uz, un, uh;
#pragma unroll
    for (int e = 0; e < 4; ++e) {
      const int k0 = kh * 32 + 8 * g + 2 * e;
      const f32x4 w0 = WcF[k0][u];
      const f32x4 w1 = WcF[k0 + 1][u];
      ur.w[e] = cvtpk(w0.x, w1.x);
      uz.w[e] = cvtpk(w0.y, w1.y);
      un.w[e] = cvtpk(w0.z, w1.z);
      uh.w[e] = cvtpk(w0.w, w1.w);
    }
    Br[kh] = ur.v; Bz[kh] = uz.v; Bn[kh] = un.v; Bh[kh] = uh.v;
  }
  if (wid == 0) {
#pragma unroll
    for (int kh = 0; kh < 2; ++kh) {
      U ux;
#pragma unroll
      for (int e = 0; e < 4; ++e) {
        const int k0 = kh * 32 + 8 * g + 2 * e;
        ux.w[e] = cvtpk(WlF[k0][c16], WlF[k0 + 1][c16]);
      }
      Bx[kh] = ux.v;
    }
  }

  // ---- t = 1 bootstrap: h1 from x0 (h0 == 0); fake rows run on zeros ----
  float h_r[4];
#pragma unroll
  for (int j = 0; j < 4; ++j) {
    const int rl = 4 * g + j;
    float gr = 0.0f, gz = 0.0f, gn = 0.0f;
#pragma unroll
    for (int f = 0; f < 16; ++f) {
      const float xr = lds_x0[rl][f];
      gr = fmaf(w_ih[u * 16 + f], xr, gr);
      gz = fmaf(w_ih[(64 + u) * 16 + f], xr, gz);
      gn = fmaf(w_ih[(128 + u) * 16 + f], xr, gn);
    }
    const float rr = sigm(gr + b_ih[u] + b_hh[u]);
    const float zz = sigm(gz + b_ih[64 + u] + b_hh[64 + u]);
    const float nn = tanh_f(gn + b_ih[128 + u] + rr * b_hh[128 + u]);
    h_r[j] = nn - zz * nn;
    lds_h[1][rl][u] = (u16)cvtpk(h_r[j], h_r[j]);   // h1 -> buf 1
  }
  __syncthreads();

  // ---- main loop: h_i (buf i&1) -> x_i (slice i, wave0 rows 0-7) + h_{i+1} ----
  for (int i = 1; i < T; ++i) {
    const int p = i & 1;
    const bf16x8 a0 = *(const bf16x8*)&lds_h[p][c16][8 * g];
    const bf16x8 a1 = *(const bf16x8*)&lds_h[p][c16][32 + 8 * g];

    f32x4 ar = {b_r, b_r, b_r, b_r};
    f32x4 az = {b_z, b_z, b_z, b_z};
    f32x4 an = {b_n, b_n, b_n, b_n};
    f32x4 ah = {b_hn, b_hn, b_hn, b_hn};
    ar = __builtin_amdgcn_mfma_f32_16x16x32_bf16(a0, Br[0], ar, 0, 0, 0);
    ar = __builtin_amdgcn_mfma_f32_16x16x32_bf16(a1, Br[1], ar, 0, 0, 0);
    az = __builtin_amdgcn_mfma_f32_16x16x32_bf16(a0, Bz[0], az, 0, 0, 0);
    az = __builtin_amdgcn_mfma_f32_16x16x32_bf16(a1, Bz[1], az, 0, 0, 0);
    an = __builtin_amdgcn_mfma_f32_16x16x32_bf16(a0, Bn[0], an, 0, 0, 0);
    an = __builtin_amdgcn_mfma_f32_16x16x32_bf16(a1, Bn[1], an, 0, 0, 0);
    ah = __builtin_amdgcn_mfma_f32_16x16x32_bf16(a0, Bh[0], ah, 0, 0, 0);
    ah = __builtin_amdgcn_mfma_f32_16x16x32_bf16(a1, Bh[1], ah, 0, 0, 0);

    if (wid == 0) {   // x_i = Wl . h_i (+blin); store only real rows (g<2)
      f32x4 ax = {b_x, b_x, b_x, b_x};
      ax = __builtin_amdgcn_mfma_f32_16x16x32_bf16(a0, Bx[0], ax, 0, 0, 0);
      ax = __builtin_amdgcn_mfma_f32_16x16x32_bf16(a1, Bx[1], ax, 0, 0, 0);
      if (g < 2) {
#pragma unroll
        for (int j = 0; j < 4; ++j)
          out[(size_t)i * (BATCH * NFEAT) + (size_t)(r0 + 4 * g + j) * 16 + c16] = ax[j];
      }
    }

#pragma unroll
    for (int j = 0; j < 4; ++j) {
      const float rr = sigm(ar[j]);
      const float zz = sigm(az[j]);
      const float nn = tanh_f(fmaf(rr, ah[j], an[j]));
      h_r[j] = fmaf(zz, h_r[j] - nn, nn);
      lds_h[p ^ 1][4 * g + j][u] = (u16)cvtpk(h_r[j], h_r[j]);
    }
    __syncthreads();
  }
}

extern "C" void kernel_launch(void* const* d_in, const int* in_sizes, int n_in,
                              void* d_out, int out_size, void* d_ws, size_t ws_size,
                              hipStream_t stream) {
  // Size-keyed pointer resolution (validated rounds 3-16).
  int ix = -1, it = -1, iwih = -1, iwhh = -1, ibih = -1, ibhh = -1, iwlin = -1, iblin = -1;
  bool ok = (n_in == 8);
  if (ok) {
    for (int i = 0; i < 8; ++i) {
      switch (in_sizes[i]) {
        case 65536: ix = i; break;
        case 1000:  it = i; break;
        case 3072:  iwih = i; break;
        case 12288: iwhh = i; break;
        case 192:   if (ibih < 0) ibih = i; else ibhh = i; break;
        case 1024:  iwlin = i; break;
        case 16:    iblin = i; break;
        default: ok = false;
      }
    }
  }
  float* out = (float*)d_out;
  if (!ok || ix < 0 || it < 0 || iwih < 0 || iwhh < 0 || ibih < 0 || ibhh < 0 ||
      iwlin < 0 || iblin < 0) {
    fill_const<<<256, 256, 0, stream>>>(out, out_size, 1000.0f);
    return;
  }
  const int T = in_sizes[it];
  if ((size_t)T * BATCH * NFEAT != (size_t)out_size) {
    fill_const<<<256, 256, 0, stream>>>(out, out_size, 500.0f);
    return;
  }

  gru_mfma4<<<dim3(NBLK), dim3(256), 0, stream>>>(
      (const float*)d_in[ix], (const float*)d_in[iwih], (const float*)d_in[iwhh],
      (const float*)d_in[ibih], (const float*)d_in[ibhh], (const float*)d_in[iwlin],
      (const float*)d_in[iblin], out, T);
}

// Round 18
// 655.247 us; speedup vs baseline: 1.4976x; 1.4976x over previous
//
#include <hip/hip_runtime.h>
#include <stdint.h>

typedef unsigned short u16;
typedef unsigned int u32;
typedef __attribute__((ext_vector_type(8))) short bf16x8;
typedef __attribute__((ext_vector_type(4))) float f32x4;

#define BATCH 4096
#define NFEAT 16
#define NBLK 256                 // 16 real rows per block, 8 waves (j-split pairs)

__device__ __forceinline__ float sigm(float v) { return 1.0f / (1.0f + __expf(-v)); }
__device__ __forceinline__ float tanh_f(float v) { return 1.0f - 2.0f / (__expf(2.0f * v) + 1.0f); }
__device__ __forceinline__ u32 cvtpk(float lo, float hi) {  // 2x f32 -> packed bf16 (RNE)
  u32 d;
  asm("v_cvt_pk_bf16_f32 %0, %1, %2" : "=v"(d) : "v"(lo), "v"(hi));
  return d;
}

__global__ void fill_const(float* out, int n, float c) {
  for (int i = blockIdx.x * blockDim.x + threadIdx.x; i < n; i += gridDim.x * blockDim.x)
    out[i] = c;
}

// R18: j-split wave pairing. 256 blocks x 8 waves. Wave pair p = wid>>1 owns
// units 16p..16p+15; BOTH waves of the pair compute the same 8 MFMAs
// (redundant - MFMA pipe is underused); epilogue splits by acc reg index:
// half = wid&1 processes j in {2*half, 2*half+1} (rows 4g+2half+{0,1}),
// all 64 lanes active, 2 cells/lane. Per-SIMD VALU issue == R16, but
// 2 waves/SIMD overlap latencies. Waves 0,1 add the x-tile (their j-rows).
// h double-buffered in LDS; one __syncthreads per step. Math bit-identical R16.
__global__ __launch_bounds__(512, 1) void gru_mfma8(
    const float* __restrict__ x_in, const float* __restrict__ w_ih,
    const float* __restrict__ w_hh, const float* __restrict__ b_ih,
    const float* __restrict__ b_hh, const float* __restrict__ w_lin,
    const float* __restrict__ b_lin, float* __restrict__ out, int T) {
  __shared__ f32x4 WcF[64][64];     // [k][u] folded (r,z,nin,nhh) f32   64 KB
  __shared__ float WlF[64][16];     // [k][f] w_lin^T                     4 KB
  __shared__ u16 lds_h[2][16][72];  // h bf16 double buffer             4.6 KB
  __shared__ float lds_x0[16][17];  // x0 tile                          1.1 KB

  const int tid = threadIdx.x;
  const int wid = tid >> 6;        // 0..7
  const int pair = wid >> 1;       // unit-column group 0..3
  const int half = wid & 1;        // j-split: j in {2half, 2half+1}
  const int l = tid & 63;
  const int g = l >> 4;            // k-octet group / C row-group
  const int c16 = l & 15;          // col-in-tile / row-in-A
  const int r0 = blockIdx.x * 16;
  const int u = pair * 16 + c16;   // owned unit column

  // ---- slice-0 passthrough + x0 stage ----
  if (tid < 256) {
    const float v = x_in[r0 * 16 + tid];
    lds_x0[tid >> 4][tid & 15] = v;
    out[(size_t)r0 * 16 + tid] = v;
  }

  // ---- cooperative weight fold (half==0 waves only; k = lane, 16 units/pair) ----
  if (half == 0) {
    const int k = l;
    float wl16[16];
#pragma unroll
    for (int f = 0; f < 16; ++f) wl16[f] = w_lin[f * 64 + k];
    if (wid == 0) {
#pragma unroll
      for (int f = 0; f < 16; ++f) WlF[k][f] = wl16[f];
    }
    for (int uu = pair * 16; uu < pair * 16 + 16; ++uu) {
      float fr = w_hh[uu * 64 + k];
      float fz = w_hh[(64 + uu) * 64 + k];
      float fn = 0.0f;
#pragma unroll
      for (int f = 0; f < 16; ++f) {
        fr = fmaf(w_ih[uu * 16 + f], wl16[f], fr);
        fz = fmaf(w_ih[(64 + uu) * 16 + f], wl16[f], fz);
        fn = fmaf(w_ih[(128 + uu) * 16 + f], wl16[f], fn);
      }
      WcF[k][uu] = (f32x4){fr, fz, fn, w_hh[(128 + uu) * 64 + k]};
    }
  }
  __syncthreads();

  // ---- per-lane folded biases for owned unit (+ x bias) ----
  float b_r = b_ih[u] + b_hh[u];
  float b_z = b_ih[64 + u] + b_hh[64 + u];
  float b_n = b_ih[128 + u];
  const float b_hn = b_hh[128 + u];
  const float b_x = b_lin[c16];
#pragma unroll
  for (int f = 0; f < 16; ++f) {
    const float bl = b_lin[f];
    b_r = fmaf(w_ih[u * 16 + f], bl, b_r);
    b_z = fmaf(w_ih[(64 + u) * 16 + f], bl, b_z);
    b_n = fmaf(w_ih[(128 + u) * 16 + f], bl, b_n);
  }

  // ---- resident B-frags for owned planes (+x for waves 0,1) ----
  union U { u32 w[4]; bf16x8 v; };
  bf16x8 Br[2], Bz[2], Bn[2], Bh[2], Bx[2];
#pragma unroll
  for (int kh = 0; kh < 2; ++kh) {
    U ur, uz, un, uh;
#pragma unroll
    for (int e = 0; e < 4; ++e) {
      const int k0 = kh * 32 + 8 * g + 2 * e;
      const f32x4 w0 = WcF[k0][u];
      const f32x4 w1 = WcF[k0 + 1][u];
      ur.w[e] = cvtpk(w0.x, w1.x);
      uz.w[e] = cvtpk(w0.y, w1.y);
      un.w[e] = cvtpk(w0.z, w1.z);
      uh.w[e] = cvtpk(w0.w, w1.w);
    }
    Br[kh] = ur.v; Bz[kh] = uz.v; Bn[kh] = un.v; Bh[kh] = uh.v;
  }
  if (pair == 0) {   // waves 0,1
#pragma unroll
    for (int kh = 0; kh < 2; ++kh) {
      U ux;
#pragma unroll
      for (int e = 0; e < 4; ++e) {
        const int k0 = kh * 32 + 8 * g + 2 * e;
        ux.w[e] = cvtpk(WlF[k0][c16], WlF[k0 + 1][c16]);
      }
      Bx[kh] = ux.v;
    }
  }

  // ---- t = 1 bootstrap: h1 from x0 (h0 == 0); this wave's 2 j-cells only ----
  float h_s[2];
#pragma unroll
  for (int jj = 0; jj < 2; ++jj) {
    const int rl = 4 * g + 2 * half + jj;
    float gr = 0.0f, gz = 0.0f, gn = 0.0f;
#pragma unroll
    for (int f = 0; f < 16; ++f) {
      const float xr = lds_x0[rl][f];
      gr = fmaf(w_ih[u * 16 + f], xr, gr);
      gz = fmaf(w_ih[(64 + u) * 16 + f], xr, gz);
      gn = fmaf(w_ih[(128 + u) * 16 + f], xr, gn);
    }
    const float rr = sigm(gr + b_ih[u] + b_hh[u]);
    const float zz = sigm(gz + b_ih[64 + u] + b_hh[64 + u]);
    const float nn = tanh_f(gn + b_ih[128 + u] + rr * b_hh[128 + u]);
    h_s[jj] = nn - zz * nn;
    lds_h[1][rl][u] = (u16)cvtpk(h_s[jj], h_s[jj]);   // h1 -> buf 1
  }
  __syncthreads();

  // ---- main loop: h_i (buf i&1) -> x_i (waves 0,1) + h_{i+1} (buf ~i&1) ----
  for (int i = 1; i < T; ++i) {
    const int p = i & 1;
    const bf16x8 a0 = *(const bf16x8*)&lds_h[p][c16][8 * g];
    const bf16x8 a1 = *(const bf16x8*)&lds_h[p][c16][32 + 8 * g];

    f32x4 ar = {b_r, b_r, b_r, b_r};
    f32x4 az = {b_z, b_z, b_z, b_z};
    f32x4 an = {b_n, b_n, b_n, b_n};
    f32x4 ah = {b_hn, b_hn, b_hn, b_hn};
    ar = __builtin_amdgcn_mfma_f32_16x16x32_bf16(a0, Br[0], ar, 0, 0, 0);
    ar = __builtin_amdgcn_mfma_f32_16x16x32_bf16(a1, Br[1], ar, 0, 0, 0);
    az = __builtin_amdgcn_mfma_f32_16x16x32_bf16(a0, Bz[0], az, 0, 0, 0);
    az = __builtin_amdgcn_mfma_f32_16x16x32_bf16(a1, Bz[1], az, 0, 0, 0);
    an = __builtin_amdgcn_mfma_f32_16x16x32_bf16(a0, Bn[0], an, 0, 0, 0);
    an = __builtin_amdgcn_mfma_f32_16x16x32_bf16(a1, Bn[1], an, 0, 0, 0);
    ah = __builtin_amdgcn_mfma_f32_16x16x32_bf16(a0, Bh[0], ah, 0, 0, 0);
    ah = __builtin_amdgcn_mfma_f32_16x16x32_bf16(a1, Bh[1], ah, 0, 0, 0);

    if (pair == 0) {   // x_i tile (redundant in waves 0,1); store own j-rows
      f32x4 ax = {b_x, b_x, b_x, b_x};
      ax = __builtin_amdgcn_mfma_f32_16x16x32_bf16(a0, Bx[0], ax, 0, 0, 0);
      ax = __builtin_amdgcn_mfma_f32_16x16x32_bf16(a1, Bx[1], ax, 0, 0, 0);
#pragma unroll
      for (int jj = 0; jj < 2; ++jj) {
        const int j = 2 * half + jj;
        out[(size_t)i * (BATCH * NFEAT) + (size_t)(r0 + 4 * g + j) * 16 + c16] = ax[j];
      }
    }

#pragma unroll
    for (int jj = 0; jj < 2; ++jj) {
      const int j = 2 * half + jj;
      const float rr = sigm(ar[j]);
      const float zz = sigm(az[j]);
      const float nn = tanh_f(fmaf(rr, ah[j], an[j]));
      h_s[jj] = fmaf(zz, h_s[jj] - nn, nn);
      lds_h[p ^ 1][4 * g + j][u] = (u16)cvtpk(h_s[jj], h_s[jj]);
    }
    __syncthreads();
  }
}

extern "C" void kernel_launch(void* const* d_in, const int* in_sizes, int n_in,
                              void* d_out, int out_size, void* d_ws, size_t ws_size,
                              hipStream_t stream) {
  // Size-keyed pointer resolution (validated rounds 3-17).
  int ix = -1, it = -1, iwih = -1, iwhh = -1, ibih = -1, ibhh = -1, iwlin = -1, iblin = -1;
  bool ok = (n_in == 8);
  if (ok) {
    for (int i = 0; i < 8; ++i) {
      switch (in_sizes[i]) {
        case 65536: ix = i; break;
        case 1000:  it = i; break;
        case 3072:  iwih = i; break;
        case 12288: iwhh = i; break;
        case 192:   if (ibih < 0) ibih = i; else ibhh = i; break;
        case 1024:  iwlin = i; break;
        case 16:    iblin = i; break;
        default: ok = false;
      }
    }
  }
  float* out = (float*)d_out;
  if (!ok || ix < 0 || it < 0 || iwih < 0 || iwhh < 0 || ibih < 0 || ibhh < 0 ||
      iwlin < 0 || iblin < 0) {
    fill_const<<<256, 256, 0, stream>>>(out, out_size, 1000.0f);
    return;
  }
  const int T = in_sizes[it];
  if ((size_t)T * BATCH * NFEAT != (size_t)out_size) {
    fill_const<<<256, 256, 0, stream>>>(out, out_size, 500.0f);
    return;
  }

  gru_mfma8<<<dim3(NBLK), dim3(512), 0, stream>>>(
      (const float*)d_in[ix], (const float*)d_in[iwih], (const float*)d_in[iwhh],
      (const float*)d_in[ibih], (const float*)d_in[ibhh], (const float*)d_in[iwlin],
      (const float*)d_in[iblin], out, T);
}

// Round 19
// 613.230 us; speedup vs baseline: 1.6002x; 1.0685x over previous
//
#include <hip/hip_runtime.h>
#include <stdint.h>

typedef unsigned short u16;
typedef unsigned int u32;
typedef __attribute__((ext_vector_type(8))) short bf16x8;
typedef __attribute__((ext_vector_type(4))) float f32x4;

#define BATCH 4096
#define NFEAT 16
#define ROWS 8
#define NBLK (BATCH / ROWS)      // 512 blocks, 2 blocks/CU -> 2 independent chains/SIMD

__device__ __forceinline__ float sigm(float v) { return 1.0f / (1.0f + __expf(-v)); }
__device__ __forceinline__ float tanh_f(float v) { return 1.0f - 2.0f / (__expf(2.0f * v) + 1.0f); }
__device__ __forceinline__ u32 cvtpk(float lo, float hi) {  // 2x f32 -> packed bf16 (RNE)
  u32 d;
  asm("v_cvt_pk_bf16_f32 %0, %1, %2" : "=v"(d) : "v"(lo), "v"(hi));
  return d;
}
// Barrier that waits ONLY on LDS (lgkmcnt), not vmcnt: global x-stores keep
// draining in the background instead of stalling every step (default
// __syncthreads drains vmcnt(0) too). Compiler fences stop code motion.
__device__ __forceinline__ void block_sync_lds() {
  asm volatile("s_waitcnt lgkmcnt(0)" ::: "memory");
  __builtin_amdgcn_s_barrier();
  asm volatile("" ::: "memory");
}

__global__ void fill_const(float* out, int n, float c) {
  for (int i = blockIdx.x * blockDim.x + threadIdx.x; i < n; i += gridDim.x * blockDim.x)
    out[i] = c;
}

// R19: j-register row packing. Block owns 8 batch rows mapped to C-reg j in
// {0,1}: tile_row(g,j) = 4g+j <-> global row r0 + 2g + j; tile rows j in {2,3}
// are permanently-zero fakes -> epilogue/h-write cost is truly halved (register
// -indexed, not lane-masked). 512 blocks x 4 waves; wave wid owns units
// 16wid..16wid+15 (8 MFMAs); wave 0 adds the x-tile. h double-buffered in LDS;
// per-step sync = lgkmcnt-only barrier. Per-row math bit-identical to R16.
__global__ __launch_bounds__(256, 2) void gru_mfma4(
    const float* __restrict__ x_in, const float* __restrict__ w_ih,
    const float* __restrict__ w_hh, const float* __restrict__ b_ih,
    const float* __restrict__ b_hh, const float* __restrict__ w_lin,
    const float* __restrict__ b_lin, float* __restrict__ out, int T) {
  __shared__ f32x4 WcF[64][64];     // [k][u] folded (r,z,nin,nhh) f32   64 KB
  __shared__ float WlF[64][16];     // [k][f] w_lin^T                     4 KB
  __shared__ u16 lds_h[2][16][72];  // h bf16 double buffer (fakes = 0) 4.5 KB
  __shared__ float lds_x0[8][17];   // x0 tile                          0.5 KB

  const int tid = threadIdx.x;
  const int wid = tid >> 6;        // wave = unit-column group 0..3
  const int l = tid & 63;
  const int g = l >> 4;            // k-octet group / C row-group
  const int c16 = l & 15;          // col-in-tile / row-in-A
  const int r0 = blockIdx.x * ROWS;
  const int u = wid * 16 + c16;    // owned unit column

  // ---- zero lds_h (both buffers incl. fake rows), stage x0, passthrough ----
  for (int e = tid; e < (int)(sizeof(lds_h) / 4); e += 256) ((u32*)lds_h)[e] = 0u;
  if (tid < ROWS * 16) {
    const float v = x_in[r0 * 16 + tid];
    lds_x0[tid >> 4][tid & 15] = v;
    out[(size_t)r0 * 16 + tid] = v;
  }

  // ---- cooperative weight fold: thread owns k = lane, u-range [16*wid,+16) ----
  {
    const int k = l;
    float wl16[16];
#pragma unroll
    for (int f = 0; f < 16; ++f) wl16[f] = w_lin[f * 64 + k];
    if (wid == 0) {
#pragma unroll
      for (int f = 0; f < 16; ++f) WlF[k][f] = wl16[f];
    }
    for (int uu = wid * 16; uu < wid * 16 + 16; ++uu) {
      float fr = w_hh[uu * 64 + k];
      float fz = w_hh[(64 + uu) * 64 + k];
      float fn = 0.0f;
#pragma unroll
      for (int f = 0; f < 16; ++f) {
        fr = fmaf(w_ih[uu * 16 + f], wl16[f], fr);
        fz = fmaf(w_ih[(64 + uu) * 16 + f], wl16[f], fz);
        fn = fmaf(w_ih[(128 + uu) * 16 + f], wl16[f], fn);
      }
      WcF[k][uu] = (f32x4){fr, fz, fn, w_hh[(128 + uu) * 64 + k]};
    }
  }
  __syncthreads();

  // ---- per-lane folded biases for owned unit (+ x bias) ----
  float b_r = b_ih[u] + b_hh[u];
  float b_z = b_ih[64 + u] + b_hh[64 + u];
  float b_n = b_ih[128 + u];
  const float b_hn = b_hh[128 + u];
  const float b_x = b_lin[c16];
#pragma unroll
  for (int f = 0; f < 16; ++f) {
    const float bl = b_lin[f];
    b_r = fmaf(w_ih[u * 16 + f], bl, b_r);
    b_z = fmaf(w_ih[(64 + u) * 16 + f], bl, b_z);
    b_n = fmaf(w_ih[(128 + u) * 16 + f], bl, b_n);
  }

  // ---- resident B-frags for owned planes (+x for wave 0) ----
  union U { u32 w[4]; bf16x8 v; };
  bf16x8 Br[2], Bz[2], Bn[2], Bh[2], Bx[2];
#pragma unroll
  for (int kh = 0; kh < 2; ++kh) {
    U ur, uz, un, uh;
#pragma unroll
    for (int e = 0; e < 4; ++e) {
      const int k0 = kh * 32 + 8 * g + 2 * e;
      const f32x4 w0 = WcF[k0][u];
      const f32x4 w1 = WcF[k0 + 1][u];
      ur.w[e] = cvtpk(w0.x, w1.x);
      uz.w[e] = cvtpk(w0.y, w1.y);
      un.w[e] = cvtpk(w0.z, w1.z);
      uh.w[e] = cvtpk(w0.w, w1.w);
    }
    Br[kh] = ur.v; Bz[kh] = uz.v; Bn[kh] = un.v; Bh[kh] = uh.v;
  }
  if (wid == 0) {
#pragma unroll
    for (int kh = 0; kh < 2; ++kh) {
      U ux;
#pragma unroll
      for (int e = 0; e < 4; ++e) {
        const int k0 = kh * 32 + 8 * g + 2 * e;
        ux.w[e] = cvtpk(WlF[k0][c16], WlF[k0 + 1][c16]);
      }
      Bx[kh] = ux.v;
    }
  }

  // ---- t = 1 bootstrap: h1 from x0 (h0 == 0); 2 real cells (j = 0,1) ----
  float h_s[2];
#pragma unroll
  for (int jj = 0; jj < 2; ++jj) {
    const int rl = 2 * g + jj;              // block row
    float gr = 0.0f, gz = 0.0f, gn = 0.0f;
#pragma unroll
    for (int f = 0; f < 16; ++f) {
      const float xr = lds_x0[rl][f];
      gr = fmaf(w_ih[u * 16 + f], xr, gr);
      gz = fmaf(w_ih[(64 + u) * 16 + f], xr, gz);
      gn = fmaf(w_ih[(128 + u) * 16 + f], xr, gn);
    }
    const float rr = sigm(gr + b_ih[u] + b_hh[u]);
    const float zz = sigm(gz + b_ih[64 + u] + b_hh[64 + u]);
    const float nn = tanh_f(gn + b_ih[128 + u] + rr * b_hh[128 + u]);
    h_s[jj] = nn - zz * nn;
    lds_h[1][4 * g + jj][u] = (u16)cvtpk(h_s[jj], h_s[jj]);   // h1 -> buf 1
  }
  __syncthreads();

  // ---- main loop: h_i (buf i&1) -> x_i (wave 0) + h_{i+1} (buf ~i&1) ----
  for (int i = 1; i < T; ++i) {
    const int p = i & 1;
    const bf16x8 a0 = *(const bf16x8*)&lds_h[p][c16][8 * g];
    const bf16x8 a1 = *(const bf16x8*)&lds_h[p][c16][32 + 8 * g];

    f32x4 ar = {b_r, b_r, b_r, b_r};
    f32x4 az = {b_z, b_z, b_z, b_z};
    f32x4 an = {b_n, b_n, b_n, b_n};
    f32x4 ah = {b_hn, b_hn, b_hn, b_hn};
    ar = __builtin_amdgcn_mfma_f32_16x16x32_bf16(a0, Br[0], ar, 0, 0, 0);
    ar = __builtin_amdgcn_mfma_f32_16x16x32_bf16(a1, Br[1], ar, 0, 0, 0);
    az = __builtin_amdgcn_mfma_f32_16x16x32_bf16(a0, Bz[0], az, 0, 0, 0);
    az = __builtin_amdgcn_mfma_f32_16x16x32_bf16(a1, Bz[1], az, 0, 0, 0);
    an = __builtin_amdgcn_mfma_f32_16x16x32_bf16(a0, Bn[0], an, 0, 0, 0);
    an = __builtin_amdgcn_mfma_f32_16x16x32_bf16(a1, Bn[1], an, 0, 0, 0);
    ah = __builtin_amdgcn_mfma_f32_16x16x32_bf16(a0, Bh[0], ah, 0, 0, 0);
    ah = __builtin_amdgcn_mfma_f32_16x16x32_bf16(a1, Bh[1], ah, 0, 0, 0);

    if (wid == 0) {   // x_i tile; store real rows (regs j = 0,1)
      f32x4 ax = {b_x, b_x, b_x, b_x};
      ax = __builtin_amdgcn_mfma_f32_16x16x32_bf16(a0, Bx[0], ax, 0, 0, 0);
      ax = __builtin_amdgcn_mfma_f32_16x16x32_bf16(a1, Bx[1], ax, 0, 0, 0);
#pragma unroll
      for (int jj = 0; jj < 2; ++jj)
        out[(size_t)i * (BATCH * NFEAT) + (size_t)(r0 + 2 * g + jj) * 16 + c16] = ax[jj];
    }

#pragma unroll
    for (int jj = 0; jj < 2; ++jj) {        // register-indexed: real work only
      const float rr = sigm(ar[jj]);
      const float zz = sigm(az[jj]);
      const float nn = tanh_f(fmaf(rr, ah[jj], an[jj]));
      h_s[jj] = fmaf(zz, h_s[jj] - nn, nn);
      lds_h[p ^ 1][4 * g + jj][u] = (u16)cvtpk(h_s[jj], h_s[jj]);
    }
    block_sync_lds();
  }
}

extern "C" void kernel_launch(void* const* d_in, const int* in_sizes, int n_in,
                              void* d_out, int out_size, void* d_ws, size_t ws_size,
                              hipStream_t stream) {
  // Size-keyed pointer resolution (validated rounds 3-18).
  int ix = -1, it = -1, iwih = -1, iwhh = -1, ibih = -1, ibhh = -1, iwlin = -1, iblin = -1;
  bool ok = (n_in == 8);
  if (ok) {
    for (int i = 0; i < 8; ++i) {
      switch (in_sizes[i]) {
        case 65536: ix = i; break;
        case 1000:  it = i; break;
        case 3072:  iwih = i; break;
        case 12288: iwhh = i; break;
        case 192:   if (ibih < 0) ibih = i; else ibhh = i; break;
        case 1024:  iwlin = i; break;
        case 16:    iblin = i; break;
        default: ok = false;
      }
    }
  }
  float* out = (float*)d_out;
  if (!ok || ix < 0 || it < 0 || iwih < 0 || iwhh < 0 || ibih < 0 || ibhh < 0 ||
      iwlin < 0 || iblin < 0) {
    fill_const<<<256, 256, 0, stream>>>(out, out_size, 1000.0f);
    return;
  }
  const int T = in_sizes[it];
  if ((size_t)T * BATCH * NFEAT != (size_t)out_size) {
    fill_const<<<256, 256, 0, stream>>>(out, out_size, 500.0f);
    return;
  }

  gru_mfma4<<<dim3(NBLK), dim3(256), 0, stream>>>(
      (const float*)d_in[ix], (const float*)d_in[iwih], (const float*)d_in[iwhh],
      (const float*)d_in[ibih], (const float*)d_in[ibhh], (const float*)d_in[iwlin],
      (const float*)d_in[iblin], out, T);
}

// Round 20
// 382.336 us; speedup vs baseline: 2.5666x; 1.6039x over previous
//
#include <hip/hip_runtime.h>
#include <stdint.h>

typedef unsigned short u16;
typedef unsigned int u32;
typedef __attribute__((ext_vector_type(8))) short bf16x8;
typedef __attribute__((ext_vector_type(4))) float f32x4;

#define BATCH 4096
#define NFEAT 16
#define ROWS 4
#define NBLK (BATCH / ROWS)   // 1024 blocks: 4/CU, 16 waves/CU, 4 waves/SIMD
#define HSTRIDE 88            // u16/row (176 B): 2-way (free) banks on b128 reads

__device__ __forceinline__ u32 cvtpk(float lo, float hi) {  // 2x f32 -> packed bf16 RNE
  u32 d;
  asm("v_cvt_pk_bf16_f32 %0, %1, %2" : "=v"(d) : "v"(lo), "v"(hi));
  return d;
}
// lgkm-only barrier: global x-stores drain in background (no vmcnt drain).
__device__ __forceinline__ void block_sync_lds() {
  asm volatile("s_waitcnt lgkmcnt(0)" ::: "memory");
  __builtin_amdgcn_s_barrier();
  asm volatile("" ::: "memory");
}

__global__ void fill_const(float* out, int n, float c) {
  for (int i = blockIdx.x * blockDim.x + threadIdx.x; i < n; i += gridDim.x * blockDim.x)
    out[i] = c;
}

// R20: 4-row blocks, 4 waves, no weight-LDS (per-lane global fold into resident
// bf16 B-frags), prescaled gate planes (r,z: -log2e; n_in,n_hh: +2log2e) so the
// epilogue is exp2+rcp only. Wave wid owns units 16wid..16wid+15 (1 col-tile,
// 8 MFMAs); real rows live at C-reg j=0, tile-rows {0,4,8,12} <-> r0+g.
// Wave 0 adds the x-output tile. h double-buffered in LDS; 1 barrier/step.
__global__ __launch_bounds__(256, 4) void gru_mfma16(
    const float* __restrict__ x_in, const float* __restrict__ w_ih,
    const float* __restrict__ w_hh, const float* __restrict__ b_ih,
    const float* __restrict__ b_hh, const float* __restrict__ w_lin,
    const float* __restrict__ b_lin, float* __restrict__ out, int T) {
  __shared__ float Wlin[64][17];         // [k][f] w_lin^T (padded)   4.25 KB
  __shared__ u16 lds_h[2][16][HSTRIDE];  // h bf16 dbuf, rows!=4m = 0  5.5 KB

  const int tid = threadIdx.x;
  const int wid = tid >> 6;
  const int l = tid & 63;
  const int g = l >> 4;            // k-octet group / C row-group
  const int c16 = l & 15;          // col-in-tile / A-row
  const int r0 = blockIdx.x * ROWS;
  const int u = wid * 16 + c16;    // owned unit column

  // zero lds_h (both buffers), stage Wlin, t=0 passthrough
  for (int e = tid; e < (int)(sizeof(lds_h) / 4); e += 256) ((u32*)lds_h)[e] = 0u;
  for (int e = tid; e < 64 * 16; e += 256)
    Wlin[e >> 4][e & 15] = w_lin[(e & 15) * 64 + (e >> 4)];
  if (tid < ROWS * NFEAT) out[(size_t)r0 * NFEAT + tid] = x_in[r0 * NFEAT + tid];
  __syncthreads();

  const float NL2E = -1.44269504088896340736f;   // -log2(e)
  const float P2L2E = 2.88539008177792681472f;   // 2*log2(e)

  // ---- per-lane fold -> resident prescaled bf16 B-frags (one-time, L2-fed) ----
  union Upk { u32 w[4]; bf16x8 v; };
  bf16x8 Br[2], Bz[2], Bn[2], Bh[2], Bx[2];
#pragma unroll
  for (int kh = 0; kh < 2; ++kh) {
    Upk ur, uz, un, uh;
#pragma unroll
    for (int e = 0; e < 4; ++e) {
      float fr2[2], fz2[2], fn2[2], fh2[2];
#pragma unroll
      for (int s = 0; s < 2; ++s) {
        const int k = kh * 32 + 8 * g + 2 * e + s;
        float fr = w_hh[u * 64 + k];
        float fz = w_hh[(64 + u) * 64 + k];
        float fn = 0.0f;
        for (int f = 0; f < 16; ++f) {
          const float wl = Wlin[k][f];
          fr = fmaf(w_ih[u * 16 + f], wl, fr);
          fz = fmaf(w_ih[(64 + u) * 16 + f], wl, fz);
          fn = fmaf(w_ih[(128 + u) * 16 + f], wl, fn);
        }
        fr2[s] = fr * NL2E;
        fz2[s] = fz * NL2E;
        fn2[s] = fn * P2L2E;
        fh2[s] = w_hh[(128 + u) * 64 + k] * P2L2E;
      }
      ur.w[e] = cvtpk(fr2[0], fr2[1]);
      uz.w[e] = cvtpk(fz2[0], fz2[1]);
      un.w[e] = cvtpk(fn2[0], fn2[1]);
      uh.w[e] = cvtpk(fh2[0], fh2[1]);
    }
    Br[kh] = ur.v; Bz[kh] = uz.v; Bn[kh] = un.v; Bh[kh] = uh.v;
  }
  if (wid == 0) {   // x-plane: B[k][col=f=c16] = w_lin[c16][k] (unscaled)
#pragma unroll
    for (int kh = 0; kh < 2; ++kh) {
      Upk ux;
#pragma unroll
      for (int e = 0; e < 4; ++e) {
        const int k0 = kh * 32 + 8 * g + 2 * e;
        ux.w[e] = cvtpk(Wlin[k0][c16], Wlin[k0 + 1][c16]);
      }
      Bx[kh] = ux.v;
    }
  }
  // prescaled folded biases
  float b_r, b_z, b_n, b_hn, b_x;
  {
    float sr = b_ih[u] + b_hh[u];
    float sz = b_ih[64 + u] + b_hh[64 + u];
    float sn = b_ih[128 + u];
#pragma unroll
    for (int f = 0; f < 16; ++f) {
      const float bl = b_lin[f];
      sr = fmaf(w_ih[u * 16 + f], bl, sr);
      sz = fmaf(w_ih[(64 + u) * 16 + f], bl, sz);
      sn = fmaf(w_ih[(128 + u) * 16 + f], bl, sn);
    }
    b_r = sr * NL2E; b_z = sz * NL2E; b_n = sn * P2L2E;
    b_hn = b_hh[128 + u] * P2L2E;
    b_x = b_lin[c16];
  }

  // ---- t = 1 bootstrap: h1 from x0 (h0 == 0); 1 cell (row r0+g, unit u) ----
  float h_s;
  {
    float gr = b_ih[u] + b_hh[u];
    float gz = b_ih[64 + u] + b_hh[64 + u];
    float gn = b_ih[128 + u];
#pragma unroll
    for (int f = 0; f < 16; ++f) {
      const float xr = x_in[(r0 + g) * 16 + f];
      gr = fmaf(w_ih[u * 16 + f], xr, gr);
      gz = fmaf(w_ih[(64 + u) * 16 + f], xr, gz);
      gn = fmaf(w_ih[(128 + u) * 16 + f], xr, gn);
    }
    const float r = __builtin_amdgcn_rcpf(1.0f + __builtin_amdgcn_exp2f(NL2E * gr));
    const float z = __builtin_amdgcn_rcpf(1.0f + __builtin_amdgcn_exp2f(NL2E * gz));
    const float q = __builtin_amdgcn_rcpf(
        1.0f + __builtin_amdgcn_exp2f(fmaf(r, P2L2E * b_hh[128 + u], P2L2E * gn)));
    const float n = fmaf(-2.0f, q, 1.0f);
    h_s = n - z * n;
    lds_h[1][4 * g][u] = (u16)cvtpk(h_s, h_s);   // h1 -> buf 1, tile-row 4g
  }
  __syncthreads();

  // ---- main loop: h_i (buf i&1) -> x_i (wave 0) + h_{i+1} (buf ~i&1) ----
  for (int i = 1; i < T; ++i) {
    const int p = i & 1;
    const u16* hb = &lds_h[p][c16][0];
    const bf16x8 a0 = *(const bf16x8*)(hb + 8 * g);        // k = 8g..8g+7
    const bf16x8 a1 = *(const bf16x8*)(hb + 32 + 8 * g);   // k = 32+8g..

    f32x4 ar = {b_r, b_r, b_r, b_r};
    f32x4 az = {b_z, b_z, b_z, b_z};
    f32x4 an = {b_n, b_n, b_n, b_n};
    f32x4 ah = {b_hn, b_hn, b_hn, b_hn};
    ar = __builtin_amdgcn_mfma_f32_16x16x32_bf16(a0, Br[0], ar, 0, 0, 0);
    ar = __builtin_amdgcn_mfma_f32_16x16x32_bf16(a1, Br[1], ar, 0, 0, 0);
    az = __builtin_amdgcn_mfma_f32_16x16x32_bf16(a0, Bz[0], az, 0, 0, 0);
    az = __builtin_amdgcn_mfma_f32_16x16x32_bf16(a1, Bz[1], az, 0, 0, 0);
    an = __builtin_amdgcn_mfma_f32_16x16x32_bf16(a0, Bn[0], an, 0, 0, 0);
    an = __builtin_amdgcn_mfma_f32_16x16x32_bf16(a1, Bn[1], an, 0, 0, 0);
    ah = __builtin_amdgcn_mfma_f32_16x16x32_bf16(a0, Bh[0], ah, 0, 0, 0);
    ah = __builtin_amdgcn_mfma_f32_16x16x32_bf16(a1, Bh[1], ah, 0, 0, 0);

    if (wid == 0) {   // x_i tile; every lane stores 1 value (256 B/block)
      f32x4 ax = {b_x, b_x, b_x, b_x};
      ax = __builtin_amdgcn_mfma_f32_16x16x32_bf16(a0, Bx[0], ax, 0, 0, 0);
      ax = __builtin_amdgcn_mfma_f32_16x16x32_bf16(a1, Bx[1], ax, 0, 0, 0);
      out[(size_t)i * (BATCH * NFEAT) + (size_t)(r0 + g) * 16 + c16] = ax[0];
    }

    // epilogue, 1 real cell (reg j=0): 3 exp2 + 3 rcp + 7 VALU
    {
      const float r = __builtin_amdgcn_rcpf(1.0f + __builtin_amdgcn_exp2f(ar[0]));
      const float z = __builtin_amdgcn_rcpf(1.0f + __builtin_amdgcn_exp2f(az[0]));
      const float q = __builtin_amdgcn_rcpf(
          1.0f + __builtin_amdgcn_exp2f(fmaf(r, ah[0], an[0])));
      const float n = fmaf(-2.0f, q, 1.0f);
      h_s = fmaf(z, h_s - n, n);
      lds_h[p ^ 1][4 * g][u] = (u16)cvtpk(h_s, h_s);
    }
    block_sync_lds();
  }
}

extern "C" void kernel_launch(void* const* d_in, const int* in_sizes, int n_in,
                              void* d_out, int out_size, void* d_ws, size_t ws_size,
                              hipStream_t stream) {
  // Size-keyed pointer resolution (validated rounds 3-19).
  int ix = -1, it = -1, iwih = -1, iwhh = -1, ibih = -1, ibhh = -1, iwlin = -1, iblin = -1;
  bool ok = (n_in == 8);
  if (ok) {
    for (int i = 0; i < 8; ++i) {
      switch (in_sizes[i]) {
        case 65536: ix = i; break;
        case 1000:  it = i; break;
        case 3072:  iwih = i; break;
        case 12288: iwhh = i; break;
        case 192:   if (ibih < 0) ibih = i; else ibhh = i; break;
        case 1024:  iwlin = i; break;
        case 16:    iblin = i; break;
        default: ok = false;
      }
    }
  }
  float* out = (float*)d_out;
  if (!ok || ix < 0 || it < 0 || iwih < 0 || iwhh < 0 || ibih < 0 || ibhh < 0 ||
      iwlin < 0 || iblin < 0) {
    fill_const<<<256, 256, 0, stream>>>(out, out_size, 1000.0f);
    return;
  }
  const int T = in_sizes[it];
  if ((size_t)T * BATCH * NFEAT != (size_t)out_size) {
    fill_const<<<256, 256, 0, stream>>>(out, out_size, 500.0f);
    return;
  }

  gru_mfma16<<<dim3(NBLK), dim3(256), 0, stream>>>(
      (const float*)d_in[ix], (const float*)d_in[iwih], (const float*)d_in[iwhh],
      (const float*)d_in[ibih], (const float*)d_in[ibhh], (const float*)d_in[iwlin],
      (const float*)d_in[iblin], out, T);
}

// Round 21
// 300.260 us; speedup vs baseline: 3.2682x; 1.2733x over previous
//
#include <hip/hip_runtime.h>
#include <stdint.h>

typedef unsigned short u16;
typedef unsigned int u32;
typedef __attribute__((ext_vector_type(8))) short bf16x8;
typedef __attribute__((ext_vector_type(4))) float f32x4;

#define BATCH 4096
#define NFEAT 16
#define ROWS 8
#define NBLK (BATCH / ROWS)   // 512 blocks: 2/CU, 8 waves/CU, 2 waves/SIMD

__device__ __forceinline__ u32 cvtpk(float lo, float hi) {  // 2x f32 -> packed bf16 RNE
  u32 d;
  asm("v_cvt_pk_bf16_f32 %0, %1, %2" : "=v"(d) : "v"(lo), "v"(hi));
  return d;
}
// lgkm-only barrier: global x-stores drain in background (no vmcnt drain).
__device__ __forceinline__ void block_sync_lds() {
  asm volatile("s_waitcnt lgkmcnt(0)" ::: "memory");
  __builtin_amdgcn_s_barrier();
  asm volatile("" ::: "memory");
}
// Swizzled h-layout: [16 rows][64 u16] per buffer; 16B blocks XOR'd by row.
// Write cell (row, u):  logical block u>>3 -> physical (u>>3)^(row&7).
// Read A-frag (c16, g): logical block g (a0) / g^4 (a1) of row c16.
__device__ __forceinline__ int h_woff(int row, int uu) {
  return row * 128 + ((((uu >> 3) ^ (row & 7))) << 4) + ((uu & 7) << 1);
}
__device__ __forceinline__ int h_roff(int c16, int g) {
  return c16 * 128 + ((g ^ (c16 & 7)) << 4);
}

__global__ void fill_const(float* out, int n, float c) {
  for (int i = blockIdx.x * blockDim.x + threadIdx.x; i < n; i += gridDim.x * blockDim.x)
    out[i] = c;
}

// R21: 8-row blocks (halved MFMA vs R20), j-register packing (tile row 4g+j <->
// global row r0+2g+j, j in {0,1}; tile rows 4g+{2,3} zero fakes), prescaled
// exp2/rcp epilogue, per-lane global weight fold into resident bf16 B-frags,
// XOR-swizzled double-buffered h in LDS, lgkm-only barrier (1/step).
// Wave wid owns units 16wid..16wid+15 (8 MFMAs); wave 0 adds the x-tile.
__global__ __launch_bounds__(256, 2) void gru_mfma8r(
    const float* __restrict__ x_in, const float* __restrict__ w_ih,
    const float* __restrict__ w_hh, const float* __restrict__ b_ih,
    const float* __restrict__ b_hh, const float* __restrict__ w_lin,
    const float* __restrict__ b_lin, float* __restrict__ out, int T) {
  __shared__ float Wlin[64][17];     // [k][f] w_lin^T (padded)      4.25 KB
  __shared__ u16 lds_h[2][16 * 64];  // swizzled h dbuf (fakes = 0)     8 KB

  const int tid = threadIdx.x;
  const int wid = tid >> 6;
  const int l = tid & 63;
  const int g = l >> 4;            // k-octet group / C row-group
  const int c16 = l & 15;          // col-in-tile / A-row
  const int r0 = blockIdx.x * ROWS;
  const int u = wid * 16 + c16;    // owned unit column

  // zero lds_h (both buffers), stage Wlin, t=0 passthrough
  for (int e = tid; e < (int)(sizeof(lds_h) / 4); e += 256) ((u32*)lds_h)[e] = 0u;
  for (int e = tid; e < 64 * 16; e += 256)
    Wlin[e >> 4][e & 15] = w_lin[(e & 15) * 64 + (e >> 4)];
  if (tid < ROWS * NFEAT) out[(size_t)r0 * NFEAT + tid] = x_in[r0 * NFEAT + tid];
  __syncthreads();

  const float NL2E = -1.44269504088896340736f;   // -log2(e)
  const float P2L2E = 2.88539008177792681472f;   // 2*log2(e)

  // ---- per-lane fold -> resident prescaled bf16 B-frags (one-time, L2-fed) ----
  union Upk { u32 w[4]; bf16x8 v; };
  bf16x8 Br[2], Bz[2], Bn[2], Bh[2], Bx[2];
#pragma unroll
  for (int kh = 0; kh < 2; ++kh) {
    Upk ur, uz, un, uh;
#pragma unroll
    for (int e = 0; e < 4; ++e) {
      float fr2[2], fz2[2], fn2[2], fh2[2];
#pragma unroll
      for (int s = 0; s < 2; ++s) {
        const int k = kh * 32 + 8 * g + 2 * e + s;
        float fr = w_hh[u * 64 + k];
        float fz = w_hh[(64 + u) * 64 + k];
        float fn = 0.0f;
        for (int f = 0; f < 16; ++f) {
          const float wl = Wlin[k][f];
          fr = fmaf(w_ih[u * 16 + f], wl, fr);
          fz = fmaf(w_ih[(64 + u) * 16 + f], wl, fz);
          fn = fmaf(w_ih[(128 + u) * 16 + f], wl, fn);
        }
        fr2[s] = fr * NL2E;
        fz2[s] = fz * NL2E;
        fn2[s] = fn * P2L2E;
        fh2[s] = w_hh[(128 + u) * 64 + k] * P2L2E;
      }
      ur.w[e] = cvtpk(fr2[0], fr2[1]);
      uz.w[e] = cvtpk(fz2[0], fz2[1]);
      un.w[e] = cvtpk(fn2[0], fn2[1]);
      uh.w[e] = cvtpk(fh2[0], fh2[1]);
    }
    Br[kh] = ur.v; Bz[kh] = uz.v; Bn[kh] = un.v; Bh[kh] = uh.v;
  }
  if (wid == 0) {   // x-plane: B[k][col=f=c16] = w_lin[c16][k] (unscaled)
#pragma unroll
    for (int kh = 0; kh < 2; ++kh) {
      Upk ux;
#pragma unroll
      for (int e = 0; e < 4; ++e) {
        const int k0 = kh * 32 + 8 * g + 2 * e;
        ux.w[e] = cvtpk(Wlin[k0][c16], Wlin[k0 + 1][c16]);
      }
      Bx[kh] = ux.v;
    }
  }
  // prescaled folded biases
  float b_r, b_z, b_n, b_hn, b_x;
  {
    float sr = b_ih[u] + b_hh[u];
    float sz = b_ih[64 + u] + b_hh[64 + u];
    float sn = b_ih[128 + u];
#pragma unroll
    for (int f = 0; f < 16; ++f) {
      const float bl = b_lin[f];
      sr = fmaf(w_ih[u * 16 + f], bl, sr);
      sz = fmaf(w_ih[(64 + u) * 16 + f], bl, sz);
      sn = fmaf(w_ih[(128 + u) * 16 + f], bl, sn);
    }
    b_r = sr * NL2E; b_z = sz * NL2E; b_n = sn * P2L2E;
    b_hn = b_hh[128 + u] * P2L2E;
    b_x = b_lin[c16];
  }

  // ---- t = 1 bootstrap: h1 from x0 (h0 == 0); 2 cells (rows r0+2g+j) ----
  float h_s[2];
#pragma unroll
  for (int jj = 0; jj < 2; ++jj) {
    float gr = b_ih[u] + b_hh[u];
    float gz = b_ih[64 + u] + b_hh[64 + u];
    float gn = b_ih[128 + u];
#pragma unroll
    for (int f = 0; f < 16; ++f) {
      const float xr = x_in[(r0 + 2 * g + jj) * 16 + f];
      gr = fmaf(w_ih[u * 16 + f], xr, gr);
      gz = fmaf(w_ih[(64 + u) * 16 + f], xr, gz);
      gn = fmaf(w_ih[(128 + u) * 16 + f], xr, gn);
    }
    const float r = __builtin_amdgcn_rcpf(1.0f + __builtin_amdgcn_exp2f(NL2E * gr));
    const float z = __builtin_amdgcn_rcpf(1.0f + __builtin_amdgcn_exp2f(NL2E * gz));
    const float q = __builtin_amdgcn_rcpf(
        1.0f + __builtin_amdgcn_exp2f(fmaf(r, P2L2E * b_hh[128 + u], P2L2E * gn)));
    const float n = fmaf(-2.0f, q, 1.0f);
    h_s[jj] = n - z * n;
    *(u16*)((char*)&lds_h[1][0] + h_woff(4 * g + jj, u)) = (u16)cvtpk(h_s[jj], h_s[jj]);
  }
  __syncthreads();

  // ---- main loop: h_i (buf i&1) -> x_i (wave 0) + h_{i+1} (buf ~i&1) ----
  for (int i = 1; i < T; ++i) {
    const int p = i & 1;
    const int ra = h_roff(c16, g);
    const bf16x8 a0 = *(const bf16x8*)((const char*)&lds_h[p][0] + ra);
    const bf16x8 a1 = *(const bf16x8*)((const char*)&lds_h[p][0] + (ra ^ 64));

    f32x4 ar = {b_r, b_r, b_r, b_r};
    f32x4 az = {b_z, b_z, b_z, b_z};
    f32x4 an = {b_n, b_n, b_n, b_n};
    f32x4 ah = {b_hn, b_hn, b_hn, b_hn};
    ar = __builtin_amdgcn_mfma_f32_16x16x32_bf16(a0, Br[0], ar, 0, 0, 0);
    ar = __builtin_amdgcn_mfma_f32_16x16x32_bf16(a1, Br[1], ar, 0, 0, 0);
    az = __builtin_amdgcn_mfma_f32_16x16x32_bf16(a0, Bz[0], az, 0, 0, 0);
    az = __builtin_amdgcn_mfma_f32_16x16x32_bf16(a1, Bz[1], az, 0, 0, 0);
    an = __builtin_amdgcn_mfma_f32_16x16x32_bf16(a0, Bn[0], an, 0, 0, 0);
    an = __builtin_amdgcn_mfma_f32_16x16x32_bf16(a1, Bn[1], an, 0, 0, 0);
    ah = __builtin_amdgcn_mfma_f32_16x16x32_bf16(a0, Bh[0], ah, 0, 0, 0);
    ah = __builtin_amdgcn_mfma_f32_16x16x32_bf16(a1, Bh[1], ah, 0, 0, 0);

    if (wid == 0) {   // x_i tile; store real rows (regs j = 0,1)
      f32x4 ax = {b_x, b_x, b_x, b_x};
      ax = __builtin_amdgcn_mfma_f32_16x16x32_bf16(a0, Bx[0], ax, 0, 0, 0);
      ax = __builtin_amdgcn_mfma_f32_16x16x32_bf16(a1, Bx[1], ax, 0, 0, 0);
#pragma unroll
      for (int jj = 0; jj < 2; ++jj)
        out[(size_t)i * (BATCH * NFEAT) + (size_t)(r0 + 2 * g + jj) * 16 + c16] = ax[jj];
    }

    // epilogue, 2 real cells (regs j = 0,1): exp2 + rcp only
#pragma unroll
    for (int jj = 0; jj < 2; ++jj) {
      const float r = __builtin_amdgcn_rcpf(1.0f + __builtin_amdgcn_exp2f(ar[jj]));
      const float z = __builtin_amdgcn_rcpf(1.0f + __builtin_amdgcn_exp2f(az[jj]));
      const float q = __builtin_amdgcn_rcpf(
          1.0f + __builtin_amdgcn_exp2f(fmaf(r, ah[jj], an[jj])));
      const float n = fmaf(-2.0f, q, 1.0f);
      h_s[jj] = fmaf(z, h_s[jj] - n, n);
      *(u16*)((char*)&lds_h[p ^ 1][0] + h_woff(4 * g + jj, u)) =
          (u16)cvtpk(h_s[jj], h_s[jj]);
    }
    block_sync_lds();
  }
}

extern "C" void kernel_launch(void* const* d_in, const int* in_sizes, int n_in,
                              void* d_out, int out_size, void* d_ws, size_t ws_size,
                              hipStream_t stream) {
  // Size-keyed pointer resolution (validated rounds 3-20).
  int ix = -1, it = -1, iwih = -1, iwhh = -1, ibih = -1, ibhh = -1, iwlin = -1, iblin = -1;
  bool ok = (n_in == 8);
  if (ok) {
    for (int i = 0; i < 8; ++i) {
      switch (in_sizes[i]) {
        case 65536: ix = i; break;
        case 1000:  it = i; break;
        case 3072:  iwih = i; break;
        case 12288: iwhh = i; break;
        case 192:   if (ibih < 0) ibih = i; else ibhh = i; break;
        case 1024:  iwlin = i; break;
        case 16:    iblin = i; break;
        default: ok = false;
      }
    }
  }
  float* out = (float*)d_out;
  if (!ok || ix < 0 || it < 0 || iwih < 0 || iwhh < 0 || ibih < 0 || ibhh < 0 ||
      iwlin < 0 || iblin < 0) {
    fill_const<<<256, 256, 0, stream>>>(out, out_size, 1000.0f);
    return;
  }
  const int T = in_sizes[it];
  if ((size_t)T * BATCH * NFEAT != (size_t)out_size) {
    fill_const<<<256, 256, 0, stream>>>(out, out_size, 500.0f);
    return;
  }

  gru_mfma8r<<<dim3(NBLK), dim3(256), 0, stream>>>(
      (const float*)d_in[ix], (const float*)d_in[iwih], (const float*)d_in[iwhh],
      (const float*)d_in[ibih], (const float*)d_in[ibhh], (const float*)d_in[iwlin],
      (const float*)d_in[iblin], out, T);
}